// Round 1
// baseline (118.181 us; speedup 1.0000x reference)
//
#include <hip/hip_runtime.h>

namespace {
constexpr int Bsz = 32;
constexpr int Ssz = 128;
constexpr int Hsz = 768;
constexpr int Msz = 8;     // max span width
constexpr int MHs = 6;     // holder max width
constexpr int KTs = 4;
constexpr int KHs = 4;
constexpr int NSPAN = Msz * Ssz; // 1024
}

// K1: dh[row] = emb[row,:]·wh, dt[row] = emb[row,:]·wt  (one wave per row)
__global__ __launch_bounds__(256) void row_dots_kernel(
    const float* __restrict__ emb, const float* __restrict__ wh,
    const float* __restrict__ wt, float* __restrict__ dh, float* __restrict__ dt)
{
    int gid  = blockIdx.x * 256 + threadIdx.x;
    int row  = gid >> 6;
    int lane = threadIdx.x & 63;
    if (row >= Bsz * Ssz) return;
    const float* r = emb + (size_t)row * Hsz;
    float ph = 0.f, pt = 0.f;
#pragma unroll
    for (int i = 0; i < Hsz / 64; ++i) {
        float e = r[lane + 64 * i];
        ph = fmaf(e, wh[lane + 64 * i], ph);
        pt = fmaf(e, wt[lane + 64 * i], pt);
    }
#pragma unroll
    for (int off = 32; off; off >>= 1) {
        ph += __shfl_down(ph, off);
        pt += __shfl_down(pt, off);
    }
    if (lane == 0) { dh[row] = ph; dt[row] = pt; }
}

// K2: one block per batch — scores, stable top-4, span projections, logits.
__global__ __launch_bounds__(256) void per_batch_kernel(
    const float* __restrict__ emb, const int* __restrict__ mask,
    const float* __restrict__ bh_p, const float* __restrict__ bt_p,
    const float* __restrict__ wi, const float* __restrict__ bi,
    const float* __restrict__ we, const float* __restrict__ be,
    const float* __restrict__ dh, const float* __restrict__ dt,
    float* __restrict__ out)
{
    const int b = blockIdx.x;
    const int tid = threadIdx.x;

    __shared__ float Dh[Ssz + 1], Dt[Ssz + 1];
    __shared__ float sch[NSPAN], sct[NSPAN];
    __shared__ float rv[256];
    __shared__ int   ri[256];
    __shared__ int   len_s;
    __shared__ int   sel[8];        // slots 0..3 targets, 4..7 holders
    __shared__ int   val[8];
    __shared__ float proj[8][8];    // targets: [0..3]=wi(4)+we_bot(4); holders: [0..3]=we_top(4)
    __shared__ float red[256 * 9];  // padded (+1) reduce scratch
    __shared__ float dsh[Ssz], dst_[Ssz];
    __shared__ int   im[Ssz];

    if (tid < Ssz) {
        dsh[tid]  = dh[b * Ssz + tid];
        dst_[tid] = dt[b * Ssz + tid];
        im[tid]   = mask[b * Ssz + tid];
    }
    __syncthreads();
    if (tid == 0) {
        int L = 0;
        for (int i = 0; i < Ssz; ++i) L += im[i];
        len_s = L;
        float ah = 0.f, at = 0.f;
        Dh[0] = 0.f; Dt[0] = 0.f;
        for (int i = 0; i < Ssz; ++i) {
            ah += dsh[i]; at += dst_[i];
            Dh[i + 1] = ah; Dt[i + 1] = at;
        }
    }
    __syncthreads();

    const int   len = len_s;
    const float bhv = bh_p[0], btv = bt_p[0];
    float* out_impl = out;                                  // [B,4,4]
    float* out_expl = out + Bsz * KTs * 4;                  // [B,16,4]
    float* out_hs   = out_expl + Bsz * KHs * KTs * 4;       // [B,1024]
    float* out_ts   = out_hs + Bsz * NSPAN;                 // [B,1024]

    // ---- span scores (hs, ts) ----
    for (int i = tid; i < NSPAN; i += 256) {
        int widx = i >> 7, st = i & (Ssz - 1), w = widx + 1;
        float h = -1.f, t = -1.f;
        if (st < len - widx) {     // span fits inside sentence
            float xt = (Dt[st + w] - Dt[st]) / (float)w + btv;
            t = 1.f / (1.f + __expf(-xt));
            if (widx < MHs) {
                float xh = (Dh[st + w] - Dh[st]) / (float)w + bhv;
                h = 1.f / (1.f + __expf(-xh));
            }
        }
        sch[i] = h; sct[i] = t;
        out_hs[b * NSPAN + i] = h;
        out_ts[b * NSPAN + i] = t;
    }
    __syncthreads();

    // ---- stable top-4 (value desc, index asc) for targets then holders ----
    for (int grp = 0; grp < 2; ++grp) {
        float* sc = (grp == 0) ? sct : sch;
        for (int k = 0; k < 4; ++k) {
            float bv = -3.f; int bidx = NSPAN;
            for (int i = tid; i < NSPAN; i += 256) {   // ascending scan: '>' keeps lowest idx
                float v = sc[i];
                if (v > bv) { bv = v; bidx = i; }
            }
            rv[tid] = bv; ri[tid] = bidx;
            __syncthreads();
            for (int s2 = 128; s2; s2 >>= 1) {
                if (tid < s2) {
                    float v2 = rv[tid + s2]; int i2 = ri[tid + s2];
                    if (v2 > rv[tid] || (v2 == rv[tid] && i2 < ri[tid])) {
                        rv[tid] = v2; ri[tid] = i2;
                    }
                }
                __syncthreads();
            }
            if (tid == 0) {
                int slot = grp * 4 + k;
                sel[slot] = ri[0];
                val[slot] = (rv[0] > 0.f) ? 1 : 0;
                sc[ri[0]] = -3.f;   // exclude from later passes
            }
            __syncthreads();
        }
    }

    // ---- projections of selected span reps ----
    for (int slot = 0; slot < 8; ++slot) {
        float acc[8] = {0.f, 0.f, 0.f, 0.f, 0.f, 0.f, 0.f, 0.f};
        if (val[slot]) {            // block-uniform branch
            int idx = sel[slot];
            int w = (idx >> 7) + 1, st = idx & (Ssz - 1);
            const float* base = emb + ((size_t)b * Ssz + st) * Hsz;
            for (int d = tid; d < Hsz; d += 256) {
                float s = 0.f;
                for (int r = 0; r < w; ++r) s += base[r * Hsz + d];
                float rep = s / (float)w;
                if (slot < 4) {     // target: project with wi and we bottom half
                    const float* wib = wi + (size_t)d * 4;
                    const float* web = we + (size_t)(Hsz + d) * 4;
                    for (int c = 0; c < 4; ++c) {
                        acc[c]     = fmaf(rep, wib[c], acc[c]);
                        acc[4 + c] = fmaf(rep, web[c], acc[4 + c]);
                    }
                } else {            // holder: project with we top half
                    const float* web = we + (size_t)d * 4;
                    for (int c = 0; c < 4; ++c) acc[c] = fmaf(rep, web[c], acc[c]);
                }
            }
        }
        for (int c = 0; c < 8; ++c) red[tid * 9 + c] = acc[c];
        __syncthreads();
        for (int s2 = 128; s2; s2 >>= 1) {
            if (tid < s2)
                for (int c = 0; c < 8; ++c) red[tid * 9 + c] += red[(tid + s2) * 9 + c];
            __syncthreads();
        }
        if (tid < 8) proj[slot][tid] = red[tid];
        __syncthreads();
    }

    // ---- final logits ----
    if (tid < 16) {                 // implicit: [4 targets][4 cols]
        int k = tid >> 2, c = tid & 3;
        float v = bi[c];
        if (val[k]) v += proj[k][c];
        out_impl[b * 16 + tid] = v;
    }
    if (tid < 64) {                 // explicit: [4 holders][4 targets][4 cols]
        int j = tid >> 4, k = (tid >> 2) & 3, c = tid & 3;
        float v = be[c];
        if (val[4 + j] && val[k]) v += proj[4 + j][c] + proj[k][4 + c];
        out_expl[b * 64 + tid] = v;
    }
}

extern "C" void kernel_launch(void* const* d_in, const int* in_sizes, int n_in,
                              void* d_out, int out_size, void* d_ws, size_t ws_size,
                              hipStream_t stream) {
    const float* emb  = (const float*)d_in[0];
    const int*   mask = (const int*)d_in[1];
    const float* wh   = (const float*)d_in[2];
    const float* bh   = (const float*)d_in[3];
    const float* wt   = (const float*)d_in[4];
    const float* bt   = (const float*)d_in[5];
    const float* wi   = (const float*)d_in[6];
    const float* bi   = (const float*)d_in[7];
    const float* we   = (const float*)d_in[8];
    const float* be   = (const float*)d_in[9];
    float* out = (float*)d_out;

    float* dh = (float*)d_ws;           // [B*S]
    float* dt = dh + Bsz * Ssz;         // [B*S]

    // one wave per row, 4 waves per block
    row_dots_kernel<<<(Bsz * Ssz) / 4, 256, 0, stream>>>(emb, wh, wt, dh, dt);
    per_batch_kernel<<<Bsz, 256, 0, stream>>>(emb, mask, bh, bt, wi, bi, we, be,
                                              dh, dt, out);
}

// Round 2
// 104.230 us; speedup vs baseline: 1.1339x; 1.1339x over previous
//
#include <hip/hip_runtime.h>

namespace {
constexpr int Bsz = 32;
constexpr int Ssz = 128;
constexpr int Hsz = 768;
constexpr int Msz = 8;     // max span width
constexpr int MHs = 6;     // holder max width
constexpr int NSPAN = Msz * Ssz; // 1024
}

__device__ __forceinline__ bool gtpair(float av, int ai, float bv, int bi) {
    // strict "ranks higher": greater value, or equal value with lower index (stable)
    return (av > bv) || (av == bv && ai < bi);
}

struct Top4 { float v[4]; int ix[4]; };

__device__ __forceinline__ void t4_init(Top4& t) {
#pragma unroll
    for (int k = 0; k < 4; ++k) { t.v[k] = -3.f; t.ix[k] = 0x7fffffff; }
}

// candidate index is strictly larger than all current entries (ascending scan),
// so ties must keep the existing entry -> insert only where strictly higher rank
__device__ __forceinline__ void t4_insert(Top4& t, float cv, int ci) {
    if (!gtpair(cv, ci, t.v[3], t.ix[3])) return;
    if (gtpair(cv, ci, t.v[2], t.ix[2])) {
        t.v[3] = t.v[2]; t.ix[3] = t.ix[2];
        if (gtpair(cv, ci, t.v[1], t.ix[1])) {
            t.v[2] = t.v[1]; t.ix[2] = t.ix[1];
            if (gtpair(cv, ci, t.v[0], t.ix[0])) {
                t.v[1] = t.v[0]; t.ix[1] = t.ix[0];
                t.v[0] = cv; t.ix[0] = ci;
            } else { t.v[1] = cv; t.ix[1] = ci; }
        } else { t.v[2] = cv; t.ix[2] = ci; }
    } else { t.v[3] = cv; t.ix[3] = ci; }
}

__device__ __forceinline__ Top4 t4_merge(const Top4& a, const Top4& b) {
    Top4 r; int pa = 0, pb = 0;
#pragma unroll
    for (int k = 0; k < 4; ++k) {
        float av = a.v[pa]; int ai = a.ix[pa];
        float bv = b.v[pb]; int bi_ = b.ix[pb];
        bool ta = gtpair(av, ai, bv, bi_);
        r.v[k] = ta ? av : bv;
        r.ix[k] = ta ? ai : bi_;
        pa += ta ? 1 : 0; pb += ta ? 0 : 1;
    }
    return r;
}

__device__ __forceinline__ Top4 t4_wave_merge(Top4 t) {
#pragma unroll
    for (int off = 1; off < 64; off <<= 1) {
        Top4 o;
#pragma unroll
        for (int k = 0; k < 4; ++k) {
            o.v[k]  = __shfl_xor(t.v[k], off);
            o.ix[k] = __shfl_xor(t.ix[k], off);
        }
        t = t4_merge(t, o);
    }
    return t;
}

// K1: dh[row] = emb[row,:]·wh, dt[row] = emb[row,:]·wt  (one wave per row, float4)
__global__ __launch_bounds__(256) void row_dots_kernel(
    const float* __restrict__ emb, const float* __restrict__ wh,
    const float* __restrict__ wt, float* __restrict__ dh, float* __restrict__ dt)
{
    int row  = blockIdx.x * 4 + (threadIdx.x >> 6);
    int lane = threadIdx.x & 63;
    const float4* r  = (const float4*)(emb + (size_t)row * Hsz);
    const float4* h4 = (const float4*)wh;
    const float4* t4 = (const float4*)wt;
    float ph = 0.f, pt = 0.f;
#pragma unroll
    for (int i = 0; i < 3; ++i) {
        float4 e = r[lane + 64 * i];
        float4 a = h4[lane + 64 * i];
        float4 c = t4[lane + 64 * i];
        ph = fmaf(e.x, a.x, fmaf(e.y, a.y, fmaf(e.z, a.z, fmaf(e.w, a.w, ph))));
        pt = fmaf(e.x, c.x, fmaf(e.y, c.y, fmaf(e.z, c.z, fmaf(e.w, c.w, pt))));
    }
#pragma unroll
    for (int off = 32; off; off >>= 1) {
        ph += __shfl_down(ph, off);
        pt += __shfl_down(pt, off);
    }
    if (lane == 0) { dh[row] = ph; dt[row] = pt; }
}

// K2: one block per batch — scores, stable top-4 via shuffle merge, projections.
__global__ __launch_bounds__(256) void per_batch_kernel(
    const float* __restrict__ emb, const int* __restrict__ mask,
    const float* __restrict__ bh_p, const float* __restrict__ bt_p,
    const float* __restrict__ wi, const float* __restrict__ bi,
    const float* __restrict__ we, const float* __restrict__ be,
    const float* __restrict__ dh, const float* __restrict__ dt,
    float* __restrict__ out)
{
    const int b = blockIdx.x;
    const int tid = threadIdx.x;
    const int wavei = tid >> 6, lane = tid & 63;

    __shared__ float dsh[Ssz], dst_[Ssz];
    __shared__ int   len_s;
    __shared__ float swv[2][4][4];
    __shared__ int   swi[2][4][4];
    __shared__ int   sel[8];       // 0..3 targets, 4..7 holders
    __shared__ int   val[8];
    __shared__ float proj[8][8];

    // phase 0: load per-row dots into LDS; wave0 computes sentence length
    if (tid < Ssz) {
        dsh[tid]  = dh[b * Ssz + tid];
        dst_[tid] = dt[b * Ssz + tid];
    }
    if (wavei == 0) {
        int m = mask[b * Ssz + lane] + mask[b * Ssz + lane + 64];
#pragma unroll
        for (int off = 32; off; off >>= 1) m += __shfl_down(m, off);
        if (lane == 0) len_s = m;
    }
    __syncthreads();                                        // barrier 1

    const int   len = len_s;
    const float bhv = bh_p[0], btv = bt_p[0];
    float* out_impl = out;                                  // [B,4,4]
    float* out_expl = out + Bsz * 16;                       // [B,16,4]
    float* out_hs   = out_expl + Bsz * 64;                  // [B,1024]
    float* out_ts   = out_hs + Bsz * NSPAN;                 // [B,1024]

    // phase 1: scores + per-thread stable top-4 (ascending index order)
    Top4 tt, th;
    t4_init(tt); t4_init(th);
#pragma unroll
    for (int q = 0; q < 4; ++q) {
        int i = tid + 256 * q;
        int widx = i >> 7, st = i & (Ssz - 1), w = widx + 1;
        float h = -1.f, t = -1.f;
        if (st < len - widx) {
            float s_t = 0.f;
            for (int r = 0; r < w; ++r) s_t += dst_[st + r];
            float xt = s_t / (float)w + btv;
            t = 1.f / (1.f + __expf(-xt));
            if (widx < MHs) {
                float s_h = 0.f;
                for (int r = 0; r < w; ++r) s_h += dsh[st + r];
                float xh = s_h / (float)w + bhv;
                h = 1.f / (1.f + __expf(-xh));
            }
        }
        out_hs[b * NSPAN + i] = h;
        out_ts[b * NSPAN + i] = t;
        t4_insert(tt, t, i);
        t4_insert(th, h, i);
    }
    tt = t4_wave_merge(tt);
    th = t4_wave_merge(th);
    if (lane == 0) {
#pragma unroll
        for (int k = 0; k < 4; ++k) {
            swv[0][wavei][k] = tt.v[k]; swi[0][wavei][k] = tt.ix[k];
            swv[1][wavei][k] = th.v[k]; swi[1][wavei][k] = th.ix[k];
        }
    }
    __syncthreads();                                        // barrier 2

    // final cross-wave merge: tid 0 -> targets (slots 0..3), tid 1 -> holders (4..7)
    if (tid < 2) {
        Top4 m;
#pragma unroll
        for (int k = 0; k < 4; ++k) { m.v[k] = swv[tid][0][k]; m.ix[k] = swi[tid][0][k]; }
        for (int w2 = 1; w2 < 4; ++w2) {
            Top4 o;
#pragma unroll
            for (int k = 0; k < 4; ++k) { o.v[k] = swv[tid][w2][k]; o.ix[k] = swi[tid][w2][k]; }
            m = t4_merge(m, o);
        }
#pragma unroll
        for (int k = 0; k < 4; ++k) {
            sel[tid * 4 + k] = m.ix[k];
            val[tid * 4 + k] = (m.v[k] > 0.f) ? 1 : 0;
        }
    }
    __syncthreads();                                        // barrier 3

    // phase 2: projections — wave handles slots {wave (target), wave+4 (holder)}
    for (int s2 = 0; s2 < 2; ++s2) {
        int slot = wavei + 4 * s2;
        float acc[8] = {0.f, 0.f, 0.f, 0.f, 0.f, 0.f, 0.f, 0.f};
        if (val[slot]) {                                    // wave-uniform branch
            int idx = sel[slot];
            int w = (idx >> 7) + 1, st = idx & (Ssz - 1);
            const float* base = emb + ((size_t)b * Ssz + st) * Hsz;
#pragma unroll
            for (int ii = 0; ii < Hsz / 64; ++ii) {
                int d = lane + 64 * ii;
                float s = 0.f;
                for (int r = 0; r < w; ++r) s += base[r * Hsz + d];
                float rep = s / (float)w;
                if (s2 == 0) {                              // target: wi + we bottom half
                    float4 w4 = ((const float4*)wi)[d];
                    float4 e4 = ((const float4*)we)[Hsz + d];
                    acc[0] = fmaf(rep, w4.x, acc[0]); acc[1] = fmaf(rep, w4.y, acc[1]);
                    acc[2] = fmaf(rep, w4.z, acc[2]); acc[3] = fmaf(rep, w4.w, acc[3]);
                    acc[4] = fmaf(rep, e4.x, acc[4]); acc[5] = fmaf(rep, e4.y, acc[5]);
                    acc[6] = fmaf(rep, e4.z, acc[6]); acc[7] = fmaf(rep, e4.w, acc[7]);
                } else {                                    // holder: we top half
                    float4 e4 = ((const float4*)we)[d];
                    acc[0] = fmaf(rep, e4.x, acc[0]); acc[1] = fmaf(rep, e4.y, acc[1]);
                    acc[2] = fmaf(rep, e4.z, acc[2]); acc[3] = fmaf(rep, e4.w, acc[3]);
                }
            }
        }
#pragma unroll
        for (int off = 32; off; off >>= 1)
#pragma unroll
            for (int c = 0; c < 8; ++c) acc[c] += __shfl_down(acc[c], off);
        if (lane == 0)
#pragma unroll
            for (int c = 0; c < 8; ++c) proj[slot][c] = acc[c];
    }
    __syncthreads();                                        // barrier 4

    // phase 3: final logits
    if (tid < 16) {                 // implicit: [4 targets][4 cols]
        int k = tid >> 2, c = tid & 3;
        out_impl[b * 16 + tid] = bi[c] + (val[k] ? proj[k][c] : 0.f);
    } else if (tid >= 64 && tid < 128) {  // explicit: [4 holders][4 targets][4 cols]
        int u = tid - 64;
        int j = u >> 4, k = (u >> 2) & 3, c = u & 3;
        float v = be[c];
        if (val[4 + j] && val[k]) v += proj[4 + j][c] + proj[k][4 + c];
        out_expl[b * 64 + u] = v;
    }
}

extern "C" void kernel_launch(void* const* d_in, const int* in_sizes, int n_in,
                              void* d_out, int out_size, void* d_ws, size_t ws_size,
                              hipStream_t stream) {
    const float* emb  = (const float*)d_in[0];
    const int*   mask = (const int*)d_in[1];
    const float* wh   = (const float*)d_in[2];
    const float* bh   = (const float*)d_in[3];
    const float* wt   = (const float*)d_in[4];
    const float* bt   = (const float*)d_in[5];
    const float* wi   = (const float*)d_in[6];
    const float* bi   = (const float*)d_in[7];
    const float* we   = (const float*)d_in[8];
    const float* be   = (const float*)d_in[9];
    float* out = (float*)d_out;

    float* dh = (float*)d_ws;           // [B*S]
    float* dt = dh + Bsz * Ssz;         // [B*S]

    row_dots_kernel<<<(Bsz * Ssz) / 4, 256, 0, stream>>>(emb, wh, wt, dh, dt);
    per_batch_kernel<<<Bsz, 256, 0, stream>>>(emb, mask, bh, bt, wi, bi, we, be,
                                              dh, dt, out);
}

// Round 3
// 97.304 us; speedup vs baseline: 1.2146x; 1.0712x over previous
//
#include <hip/hip_runtime.h>

namespace {
constexpr int Bsz = 32;
constexpr int Ssz = 128;
constexpr int Hsz = 768;
constexpr int Msz = 8;     // max span width
constexpr int MHs = 6;     // holder max width
constexpr int NSPAN = Msz * Ssz; // 1024
}

__device__ __forceinline__ bool gtpair(float av, int ai, float bv, int bi) {
    // strict "ranks higher": greater value, or equal value with lower index (stable)
    return (av > bv) || (av == bv && ai < bi);
}

struct Top4 { float v[4]; int ix[4]; };

__device__ __forceinline__ void t4_init(Top4& t) {
#pragma unroll
    for (int k = 0; k < 4; ++k) { t.v[k] = -3.f; t.ix[k] = 0x7fffffff; }
}

// candidate index is strictly larger than all current entries (ascending scan),
// so ties keep the existing entry -> insert only where strictly higher rank
__device__ __forceinline__ void t4_insert(Top4& t, float cv, int ci) {
    if (!gtpair(cv, ci, t.v[3], t.ix[3])) return;
    if (gtpair(cv, ci, t.v[2], t.ix[2])) {
        t.v[3] = t.v[2]; t.ix[3] = t.ix[2];
        if (gtpair(cv, ci, t.v[1], t.ix[1])) {
            t.v[2] = t.v[1]; t.ix[2] = t.ix[1];
            if (gtpair(cv, ci, t.v[0], t.ix[0])) {
                t.v[1] = t.v[0]; t.ix[1] = t.ix[0];
                t.v[0] = cv; t.ix[0] = ci;
            } else { t.v[1] = cv; t.ix[1] = ci; }
        } else { t.v[2] = cv; t.ix[2] = ci; }
    } else { t.v[3] = cv; t.ix[3] = ci; }
}

__device__ __forceinline__ Top4 t4_merge(const Top4& a, const Top4& b) {
    Top4 r; int pa = 0, pb = 0;
#pragma unroll
    for (int k = 0; k < 4; ++k) {
        float av = a.v[pa]; int ai = a.ix[pa];
        float bv = b.v[pb]; int bi_ = b.ix[pb];
        bool ta = gtpair(av, ai, bv, bi_);
        r.v[k] = ta ? av : bv;
        r.ix[k] = ta ? ai : bi_;
        pa += ta ? 1 : 0; pb += ta ? 0 : 1;
    }
    return r;
}

__device__ __forceinline__ Top4 t4_wave_merge(Top4 t) {
#pragma unroll
    for (int off = 1; off < 64; off <<= 1) {
        Top4 o;
#pragma unroll
        for (int k = 0; k < 4; ++k) {
            o.v[k]  = __shfl_xor(t.v[k], off);
            o.ix[k] = __shfl_xor(t.ix[k], off);
        }
        t = t4_merge(t, o);
    }
    return t;
}

// K1: dh[row] = emb[row,:]·wh, dt[row] = emb[row,:]·wt  (one wave per row, float4)
__global__ __launch_bounds__(256) void row_dots_kernel(
    const float* __restrict__ emb, const float* __restrict__ wh,
    const float* __restrict__ wt, float* __restrict__ dh, float* __restrict__ dt)
{
    int row  = blockIdx.x * 4 + (threadIdx.x >> 6);
    int lane = threadIdx.x & 63;
    const float4* r  = (const float4*)(emb + (size_t)row * Hsz);
    const float4* h4 = (const float4*)wh;
    const float4* t4 = (const float4*)wt;
    float ph = 0.f, pt = 0.f;
#pragma unroll
    for (int i = 0; i < 3; ++i) {
        float4 e = r[lane + 64 * i];
        float4 a = h4[lane + 64 * i];
        float4 c = t4[lane + 64 * i];
        ph = fmaf(e.x, a.x, fmaf(e.y, a.y, fmaf(e.z, a.z, fmaf(e.w, a.w, ph))));
        pt = fmaf(e.x, c.x, fmaf(e.y, c.y, fmaf(e.z, c.z, fmaf(e.w, c.w, pt))));
    }
#pragma unroll
    for (int off = 32; off; off >>= 1) {
        ph += __shfl_down(ph, off);
        pt += __shfl_down(pt, off);
    }
    if (lane == 0) { dh[row] = ph; dt[row] = pt; }
}

// K2: one block per batch — scores (incremental widths), shuffle top-4, batched-load projections.
__global__ __launch_bounds__(256) void per_batch_kernel(
    const float* __restrict__ emb, const int* __restrict__ mask,
    const float* __restrict__ bh_p, const float* __restrict__ bt_p,
    const float* __restrict__ wi, const float* __restrict__ bi,
    const float* __restrict__ we, const float* __restrict__ be,
    const float* __restrict__ dh, const float* __restrict__ dt,
    float* __restrict__ out)
{
    const int b = blockIdx.x;
    const int tid = threadIdx.x;
    const int wavei = tid >> 6, lane = tid & 63;

    __shared__ float dsh[Ssz], dst_[Ssz];
    __shared__ int   len_s;
    __shared__ float swv[4][4];
    __shared__ int   swi[4][4];
    __shared__ int   sel[8];       // 0..3 targets, 4..7 holders
    __shared__ int   val[8];
    __shared__ float proj[8][8];

    // phase 0: per-row dots into LDS; wave0 computes sentence length
    if (tid < Ssz) {
        dsh[tid]  = dh[b * Ssz + tid];
        dst_[tid] = dt[b * Ssz + tid];
    }
    if (wavei == 0) {
        int m = mask[b * Ssz + lane] + mask[b * Ssz + lane + 64];
#pragma unroll
        for (int off = 32; off; off >>= 1) m += __shfl_down(m, off);
        if (lane == 0) len_s = m;
    }
    __syncthreads();                                        // barrier 1

    const int   len = len_s;
    const float bhv = bh_p[0], btv = bt_p[0];
    float* out_impl = out;                                  // [B,4,4]
    float* out_expl = out + Bsz * 16;                       // [B,16,4]
    float* out_hs   = out_expl + Bsz * 64;                  // [B,1024]
    float* out_ts   = out_hs + Bsz * NSPAN;                 // [B,1024]

    // phase 1: thread = (start, grp); grp 0 (tid<128, waves 0-1) = targets,
    // grp 1 (waves 2-3) = holders. Running sum over widths 1..8 -> 8 dependent
    // LDS reads/thread; candidates generated in ascending span index (stable).
    {
        const int st  = tid & (Ssz - 1);
        const int grp = tid >> 7;
        const float* dar = grp ? dsh : dst_;
        const float  bv  = grp ? bhv : btv;
        float* outp = grp ? (out_hs + b * NSPAN) : (out_ts + b * NSPAN);
        Top4 t4l; t4_init(t4l);
        float run = 0.f;
#pragma unroll
        for (int widx = 0; widx < Msz; ++widx) {
            bool fits = (st < len - widx);
            if (fits) run += dar[st + widx];       // st+widx < len <= Ssz, in-bounds
            bool valid = fits && (grp == 0 || widx < MHs);
            float sc = -1.f;
            if (valid) {
                float x = run * (1.f / (float)(widx + 1)) + bv;
                sc = 1.f / (1.f + __expf(-x));
            }
            int i = (widx << 7) | st;
            outp[i] = sc;
            t4_insert(t4l, sc, i);
        }
        t4l = t4_wave_merge(t4l);
        if (lane == 0) {
#pragma unroll
            for (int k = 0; k < 4; ++k) { swv[wavei][k] = t4l.v[k]; swi[wavei][k] = t4l.ix[k]; }
        }
    }
    __syncthreads();                                        // barrier 2

    // cross-wave merge: tid 0 -> targets (waves 0,1 -> slots 0..3),
    //                   tid 1 -> holders (waves 2,3 -> slots 4..7)
    if (tid < 2) {
        Top4 a, c;
#pragma unroll
        for (int k = 0; k < 4; ++k) {
            a.v[k] = swv[2 * tid][k];     a.ix[k] = swi[2 * tid][k];
            c.v[k] = swv[2 * tid + 1][k]; c.ix[k] = swi[2 * tid + 1][k];
        }
        Top4 m = t4_merge(a, c);
#pragma unroll
        for (int k = 0; k < 4; ++k) {
            sel[tid * 4 + k] = m.ix[k];
            val[tid * 4 + k] = (m.v[k] > 0.f) ? 1 : 0;
        }
    }
    __syncthreads();                                        // barrier 3

    // phase 2: projections — wave handles slot wavei (target) then wavei+4 (holder).
    // All span-row loads unrolled+clamped -> independent, one latency batch per slot.
    for (int s2 = 0; s2 < 2; ++s2) {
        int slot = wavei + 4 * s2;
        float acc[8] = {0.f, 0.f, 0.f, 0.f, 0.f, 0.f, 0.f, 0.f};
        if (val[slot]) {                                    // wave-uniform branch
            int idx = sel[slot];
            int w = (idx >> 7) + 1, st = idx & (Ssz - 1);
            const float4* base = (const float4*)(emb + ((size_t)b * Ssz + st) * Hsz);
            float inv = 1.f / (float)w;
            float4 s0 = {0,0,0,0}, s1 = {0,0,0,0}, s2v = {0,0,0,0};
#pragma unroll
            for (int r = 0; r < Msz; ++r) {
                int   rr = (r < w) ? r : (w - 1);           // clamped: always a valid row
                float m_ = (r < w) ? inv : 0.f;
                const float4* rp = base + rr * (Hsz / 4);
                float4 e0 = rp[lane];
                float4 e1 = rp[lane + 64];
                float4 e2 = rp[lane + 128];
                s0.x = fmaf(e0.x, m_, s0.x); s0.y = fmaf(e0.y, m_, s0.y);
                s0.z = fmaf(e0.z, m_, s0.z); s0.w = fmaf(e0.w, m_, s0.w);
                s1.x = fmaf(e1.x, m_, s1.x); s1.y = fmaf(e1.y, m_, s1.y);
                s1.z = fmaf(e1.z, m_, s1.z); s1.w = fmaf(e1.w, m_, s1.w);
                s2v.x = fmaf(e2.x, m_, s2v.x); s2v.y = fmaf(e2.y, m_, s2v.y);
                s2v.z = fmaf(e2.z, m_, s2v.z); s2v.w = fmaf(e2.w, m_, s2v.w);
            }
            const float4* wi4 = (const float4*)wi;          // [Hsz][4] -> one float4 per row
            const float4* we4 = (const float4*)we;          // [2*Hsz][4]
#pragma unroll
            for (int ii = 0; ii < 3; ++ii) {
                float4 rep = (ii == 0) ? s0 : ((ii == 1) ? s1 : s2v);
                float reps[4] = {rep.x, rep.y, rep.z, rep.w};
                int j = lane + 64 * ii;                     // float4 index; elements 4j..4j+3
                if (s2 == 0) {                              // target: wi + we bottom half
#pragma unroll
                    for (int t = 0; t < 4; ++t) {
                        float rt = reps[t];
                        float4 a = wi4[4 * j + t];
                        float4 c = we4[Hsz + 4 * j + t];
                        acc[0] = fmaf(rt, a.x, acc[0]); acc[1] = fmaf(rt, a.y, acc[1]);
                        acc[2] = fmaf(rt, a.z, acc[2]); acc[3] = fmaf(rt, a.w, acc[3]);
                        acc[4] = fmaf(rt, c.x, acc[4]); acc[5] = fmaf(rt, c.y, acc[5]);
                        acc[6] = fmaf(rt, c.z, acc[6]); acc[7] = fmaf(rt, c.w, acc[7]);
                    }
                } else {                                    // holder: we top half
#pragma unroll
                    for (int t = 0; t < 4; ++t) {
                        float rt = reps[t];
                        float4 c = we4[4 * j + t];
                        acc[0] = fmaf(rt, c.x, acc[0]); acc[1] = fmaf(rt, c.y, acc[1]);
                        acc[2] = fmaf(rt, c.z, acc[2]); acc[3] = fmaf(rt, c.w, acc[3]);
                    }
                }
            }
        }
#pragma unroll
        for (int off = 32; off; off >>= 1)
#pragma unroll
            for (int c = 0; c < 8; ++c) acc[c] += __shfl_down(acc[c], off);
        if (lane == 0)
#pragma unroll
            for (int c = 0; c < 8; ++c) proj[slot][c] = acc[c];
    }
    __syncthreads();                                        // barrier 4

    // phase 3: final logits
    if (tid < 16) {                 // implicit: [4 targets][4 cols]
        int k = tid >> 2, c = tid & 3;
        out_impl[b * 16 + tid] = bi[c] + (val[k] ? proj[k][c] : 0.f);
    } else if (tid >= 64 && tid < 128) {  // explicit: [4 holders][4 targets][4 cols]
        int u = tid - 64;
        int j = u >> 4, k = (u >> 2) & 3, c = u & 3;
        float v = be[c];
        if (val[4 + j] && val[k]) v += proj[4 + j][c] + proj[k][4 + c];
        out_expl[b * 64 + u] = v;
    }
}

extern "C" void kernel_launch(void* const* d_in, const int* in_sizes, int n_in,
                              void* d_out, int out_size, void* d_ws, size_t ws_size,
                              hipStream_t stream) {
    const float* emb  = (const float*)d_in[0];
    const int*   mask = (const int*)d_in[1];
    const float* wh   = (const float*)d_in[2];
    const float* bh   = (const float*)d_in[3];
    const float* wt   = (const float*)d_in[4];
    const float* bt   = (const float*)d_in[5];
    const float* wi   = (const float*)d_in[6];
    const float* bi   = (const float*)d_in[7];
    const float* we   = (const float*)d_in[8];
    const float* be   = (const float*)d_in[9];
    float* out = (float*)d_out;

    float* dh = (float*)d_ws;           // [B*S]
    float* dt = dh + Bsz * Ssz;         // [B*S]

    row_dots_kernel<<<(Bsz * Ssz) / 4, 256, 0, stream>>>(emb, wh, wt, dh, dt);
    per_batch_kernel<<<Bsz, 256, 0, stream>>>(emb, mask, bh, bt, wi, bi, we, be,
                                              dh, dt, out);
}

// Round 4
// 93.869 us; speedup vs baseline: 1.2590x; 1.0366x over previous
//
#include <hip/hip_runtime.h>

namespace {
constexpr int Bsz = 32;
constexpr int Ssz = 128;
constexpr int Hsz = 768;
constexpr int Msz = 8;     // max span width
constexpr int MHs = 6;     // holder max width
constexpr int NSPAN = Msz * Ssz; // 1024
}

__device__ __forceinline__ bool gtpair(float av, int ai, float bv, int bi) {
    // strict "ranks higher": greater value, or equal value with lower index (stable)
    return (av > bv) || (av == bv && ai < bi);
}

struct Top4 { float v[4]; int ix[4]; };

__device__ __forceinline__ void t4_init(Top4& t) {
#pragma unroll
    for (int k = 0; k < 4; ++k) { t.v[k] = -3.f; t.ix[k] = 0x7fffffff; }
}

// Static-index insert: candidate (cv,ci) into sorted-descending list.
// Pure compare+select — no dynamic array subscripts (avoids scratch).
__device__ __forceinline__ void t4_insert_g(Top4& a, float cv, int ci) {
    bool g0 = gtpair(cv, ci, a.v[0], a.ix[0]);
    bool g1 = gtpair(cv, ci, a.v[1], a.ix[1]);
    bool g2 = gtpair(cv, ci, a.v[2], a.ix[2]);
    bool g3 = gtpair(cv, ci, a.v[3], a.ix[3]);
    float nv3 = g2 ? a.v[2]  : (g3 ? cv : a.v[3]);
    int   ni3 = g2 ? a.ix[2] : (g3 ? ci : a.ix[3]);
    float nv2 = g1 ? a.v[1]  : (g2 ? cv : a.v[2]);
    int   ni2 = g1 ? a.ix[1] : (g2 ? ci : a.ix[2]);
    float nv1 = g0 ? a.v[0]  : (g1 ? cv : a.v[1]);
    int   ni1 = g0 ? a.ix[0] : (g1 ? ci : a.ix[1]);
    float nv0 = g0 ? cv : a.v[0];
    int   ni0 = g0 ? ci : a.ix[0];
    a.v[0] = nv0; a.ix[0] = ni0;
    a.v[1] = nv1; a.ix[1] = ni1;
    a.v[2] = nv2; a.ix[2] = ni2;
    a.v[3] = nv3; a.ix[3] = ni3;
}

// Merge sorted-descending b into a by rank-order insertion (static indices only).
__device__ __forceinline__ void t4_merge_into(Top4& a, const Top4& b) {
#pragma unroll
    for (int k = 0; k < 4; ++k) t4_insert_g(a, b.v[k], b.ix[k]);
}

__device__ __forceinline__ Top4 t4_wave_merge(Top4 t) {
#pragma unroll
    for (int off = 1; off < 64; off <<= 1) {
        Top4 o;
#pragma unroll
        for (int k = 0; k < 4; ++k) {
            o.v[k]  = __shfl_xor(t.v[k], off);
            o.ix[k] = __shfl_xor(t.ix[k], off);
        }
        t4_merge_into(t, o);
    }
    return t;
}

// K1: dh[row] = emb[row,:]·wh, dt[row] = emb[row,:]·wt  (one wave per row, float4)
__global__ __launch_bounds__(256) void row_dots_kernel(
    const float* __restrict__ emb, const float* __restrict__ wh,
    const float* __restrict__ wt, float* __restrict__ dh, float* __restrict__ dt)
{
    int row  = blockIdx.x * 4 + (threadIdx.x >> 6);
    int lane = threadIdx.x & 63;
    const float4* r  = (const float4*)(emb + (size_t)row * Hsz);
    const float4* h4 = (const float4*)wh;
    const float4* t4 = (const float4*)wt;
    float ph = 0.f, pt = 0.f;
#pragma unroll
    for (int i = 0; i < 3; ++i) {
        float4 e = r[lane + 64 * i];
        float4 a = h4[lane + 64 * i];
        float4 c = t4[lane + 64 * i];
        ph = fmaf(e.x, a.x, fmaf(e.y, a.y, fmaf(e.z, a.z, fmaf(e.w, a.w, ph))));
        pt = fmaf(e.x, c.x, fmaf(e.y, c.y, fmaf(e.z, c.z, fmaf(e.w, c.w, pt))));
    }
#pragma unroll
    for (int off = 32; off; off >>= 1) {
        ph += __shfl_down(ph, off);
        pt += __shfl_down(pt, off);
    }
    if (lane == 0) { dh[row] = ph; dt[row] = pt; }
}

// K2: one block per batch — scores, static-network top-4, batched-load projections.
__global__ __launch_bounds__(256) void per_batch_kernel(
    const float* __restrict__ emb, const int* __restrict__ mask,
    const float* __restrict__ bh_p, const float* __restrict__ bt_p,
    const float* __restrict__ wi, const float* __restrict__ bi,
    const float* __restrict__ we, const float* __restrict__ be,
    const float* __restrict__ dh, const float* __restrict__ dt,
    float* __restrict__ out)
{
    const int b = blockIdx.x;
    const int tid = threadIdx.x;
    const int wavei = tid >> 6, lane = tid & 63;

    __shared__ float dsh[Ssz], dst_[Ssz];
    __shared__ int   len_s;
    __shared__ float swv[4][4];
    __shared__ int   swi[4][4];
    __shared__ int   sel[8];       // 0..3 targets, 4..7 holders
    __shared__ int   val[8];
    __shared__ float proj[8][8];

    // phase 0: per-row dots into LDS; wave0 computes sentence length
    if (tid < Ssz) {
        dsh[tid]  = dh[b * Ssz + tid];
        dst_[tid] = dt[b * Ssz + tid];
    }
    if (wavei == 0) {
        int m = mask[b * Ssz + lane] + mask[b * Ssz + lane + 64];
#pragma unroll
        for (int off = 32; off; off >>= 1) m += __shfl_down(m, off);
        if (lane == 0) len_s = m;
    }
    __syncthreads();                                        // barrier 1

    const int   len = len_s;
    const float bhv = bh_p[0], btv = bt_p[0];
    float* out_impl = out;                                  // [B,4,4]
    float* out_expl = out + Bsz * 16;                       // [B,16,4]
    float* out_hs   = out_expl + Bsz * 64;                  // [B,1024]
    float* out_ts   = out_hs + Bsz * NSPAN;                 // [B,1024]

    // phase 1: thread = (start, grp); grp 0 (waves 0-1) = targets,
    // grp 1 (waves 2-3) = holders. Running sum over widths 1..8; candidates
    // generated in ascending span index (stable: insert_g keeps lower index on tie).
    {
        const int st  = tid & (Ssz - 1);
        const int grp = tid >> 7;
        const float* dar = grp ? dsh : dst_;
        const float  bv  = grp ? bhv : btv;
        float* outp = grp ? (out_hs + b * NSPAN) : (out_ts + b * NSPAN);
        Top4 t4l; t4_init(t4l);
        float run = 0.f;
#pragma unroll
        for (int widx = 0; widx < Msz; ++widx) {
            bool fits = (st < len - widx);
            if (fits) run += dar[st + widx];       // st+widx < len <= Ssz, in-bounds
            bool valid = fits && (grp == 0 || widx < MHs);
            float sc = -1.f;
            if (valid) {
                float x = run * (1.f / (float)(widx + 1)) + bv;
                sc = 1.f / (1.f + __expf(-x));
            }
            int i = (widx << 7) | st;
            outp[i] = sc;
            t4_insert_g(t4l, sc, i);
        }
        t4l = t4_wave_merge(t4l);
        if (lane == 0) {
#pragma unroll
            for (int k = 0; k < 4; ++k) { swv[wavei][k] = t4l.v[k]; swi[wavei][k] = t4l.ix[k]; }
        }
    }
    __syncthreads();                                        // barrier 2

    // cross-wave merge: tid 0 -> targets (waves 0,1 -> slots 0..3),
    //                   tid 1 -> holders (waves 2,3 -> slots 4..7)
    if (tid < 2) {
        Top4 a, c;
#pragma unroll
        for (int k = 0; k < 4; ++k) {
            a.v[k] = swv[2 * tid][k];     a.ix[k] = swi[2 * tid][k];
            c.v[k] = swv[2 * tid + 1][k]; c.ix[k] = swi[2 * tid + 1][k];
        }
        t4_merge_into(a, c);
#pragma unroll
        for (int k = 0; k < 4; ++k) {
            sel[tid * 4 + k] = a.ix[k];
            val[tid * 4 + k] = (a.v[k] > 0.f) ? 1 : 0;
        }
    }
    __syncthreads();                                        // barrier 3

    // phase 2: projections — wave handles slot wavei (target) then wavei+4 (holder).
    // All span-row loads unrolled+clamped -> independent, one latency batch per slot.
    for (int s2 = 0; s2 < 2; ++s2) {
        int slot = wavei + 4 * s2;
        float acc[8] = {0.f, 0.f, 0.f, 0.f, 0.f, 0.f, 0.f, 0.f};
        if (val[slot]) {                                    // wave-uniform branch
            int idx = sel[slot];
            int w = (idx >> 7) + 1, st = idx & (Ssz - 1);
            const float4* base = (const float4*)(emb + ((size_t)b * Ssz + st) * Hsz);
            float inv = 1.f / (float)w;
            float4 s0 = {0,0,0,0}, s1 = {0,0,0,0}, s2v = {0,0,0,0};
#pragma unroll
            for (int r = 0; r < Msz; ++r) {
                int   rr = (r < w) ? r : (w - 1);           // clamped: always a valid row
                float m_ = (r < w) ? inv : 0.f;
                const float4* rp = base + rr * (Hsz / 4);
                float4 e0 = rp[lane];
                float4 e1 = rp[lane + 64];
                float4 e2 = rp[lane + 128];
                s0.x = fmaf(e0.x, m_, s0.x); s0.y = fmaf(e0.y, m_, s0.y);
                s0.z = fmaf(e0.z, m_, s0.z); s0.w = fmaf(e0.w, m_, s0.w);
                s1.x = fmaf(e1.x, m_, s1.x); s1.y = fmaf(e1.y, m_, s1.y);
                s1.z = fmaf(e1.z, m_, s1.z); s1.w = fmaf(e1.w, m_, s1.w);
                s2v.x = fmaf(e2.x, m_, s2v.x); s2v.y = fmaf(e2.y, m_, s2v.y);
                s2v.z = fmaf(e2.z, m_, s2v.z); s2v.w = fmaf(e2.w, m_, s2v.w);
            }
            const float4* wi4 = (const float4*)wi;          // [Hsz][4] -> one float4 per row
            const float4* we4 = (const float4*)we;          // [2*Hsz][4]
#pragma unroll
            for (int ii = 0; ii < 3; ++ii) {
                float4 rep = (ii == 0) ? s0 : ((ii == 1) ? s1 : s2v);
                float reps[4] = {rep.x, rep.y, rep.z, rep.w};
                int j = lane + 64 * ii;                     // float4 index; elements 4j..4j+3
                if (s2 == 0) {                              // target: wi + we bottom half
#pragma unroll
                    for (int t = 0; t < 4; ++t) {
                        float rt = reps[t];
                        float4 a = wi4[4 * j + t];
                        float4 c = we4[Hsz + 4 * j + t];
                        acc[0] = fmaf(rt, a.x, acc[0]); acc[1] = fmaf(rt, a.y, acc[1]);
                        acc[2] = fmaf(rt, a.z, acc[2]); acc[3] = fmaf(rt, a.w, acc[3]);
                        acc[4] = fmaf(rt, c.x, acc[4]); acc[5] = fmaf(rt, c.y, acc[5]);
                        acc[6] = fmaf(rt, c.z, acc[6]); acc[7] = fmaf(rt, c.w, acc[7]);
                    }
                } else {                                    // holder: we top half
#pragma unroll
                    for (int t = 0; t < 4; ++t) {
                        float rt = reps[t];
                        float4 c = we4[4 * j + t];
                        acc[0] = fmaf(rt, c.x, acc[0]); acc[1] = fmaf(rt, c.y, acc[1]);
                        acc[2] = fmaf(rt, c.z, acc[2]); acc[3] = fmaf(rt, c.w, acc[3]);
                    }
                }
            }
        }
#pragma unroll
        for (int off = 32; off; off >>= 1)
#pragma unroll
            for (int c = 0; c < 8; ++c) acc[c] += __shfl_down(acc[c], off);
        if (lane == 0)
#pragma unroll
            for (int c = 0; c < 8; ++c) proj[slot][c] = acc[c];
    }
    __syncthreads();                                        // barrier 4

    // phase 3: final logits
    if (tid < 16) {                 // implicit: [4 targets][4 cols]
        int k = tid >> 2, c = tid & 3;
        out_impl[b * 16 + tid] = bi[c] + (val[k] ? proj[k][c] : 0.f);
    } else if (tid >= 64 && tid < 128) {  // explicit: [4 holders][4 targets][4 cols]
        int u = tid - 64;
        int j = u >> 4, k = (u >> 2) & 3, c = u & 3;
        float v = be[c];
        if (val[4 + j] && val[k]) v += proj[4 + j][c] + proj[k][4 + c];
        out_expl[b * 64 + u] = v;
    }
}

extern "C" void kernel_launch(void* const* d_in, const int* in_sizes, int n_in,
                              void* d_out, int out_size, void* d_ws, size_t ws_size,
                              hipStream_t stream) {
    const float* emb  = (const float*)d_in[0];
    const int*   mask = (const int*)d_in[1];
    const float* wh   = (const float*)d_in[2];
    const float* bh   = (const float*)d_in[3];
    const float* wt   = (const float*)d_in[4];
    const float* bt   = (const float*)d_in[5];
    const float* wi   = (const float*)d_in[6];
    const float* bi   = (const float*)d_in[7];
    const float* we   = (const float*)d_in[8];
    const float* be   = (const float*)d_in[9];
    float* out = (float*)d_out;

    float* dh = (float*)d_ws;           // [B*S]
    float* dt = dh + Bsz * Ssz;         // [B*S]

    row_dots_kernel<<<(Bsz * Ssz) / 4, 256, 0, stream>>>(emb, wh, wt, dh, dt);
    per_batch_kernel<<<Bsz, 256, 0, stream>>>(emb, mask, bh, bt, wi, bi, we, be,
                                              dh, dt, out);
}